// Round 3
// baseline (697.473 us; speedup 1.0000x reference)
//
#include <hip/hip_runtime.h>
#include <hip/hip_bf16.h>

#define IN_F 4096
#define OUT_F 4096
#define M_ROWS 8192          // 4 * 2048
#define GROUP 128

#define BM 128
#define BN 128
#define BK 32

typedef __attribute__((ext_vector_type(8))) short short8;
typedef __attribute__((ext_vector_type(4))) float floatx4;

__device__ __forceinline__ unsigned short f2bf(float f) {
    unsigned int u = __builtin_bit_cast(unsigned int, f);
    u += 0x7fffu + ((u >> 16) & 1u);   // round-to-nearest-even (no NaN inputs here)
    return (unsigned short)(u >> 16);
}

__device__ __forceinline__ void load_lds16(const unsigned short* g, unsigned short* l) {
    __builtin_amdgcn_global_load_lds(
        (const __attribute__((address_space(1))) void*)g,
        (__attribute__((address_space(3))) void*)l,
        16, 0, 0);
}

// ---------------------------------------------------------------------------
// Kernel 1: x fp32 -> bf16, 8 elements/thread (coalesced both sides)
// ---------------------------------------------------------------------------
__global__ __launch_bounds__(256) void convert_x_kernel(const float* __restrict__ x,
                                                        unsigned short* __restrict__ xb) {
    size_t t = (size_t)blockIdx.x * 256 + threadIdx.x;   // t in [0, 8192*4096/8)
    const float4* src = (const float4*)x + t * 2;
    float4 a = src[0];
    float4 b = src[1];
    union { unsigned short us[8]; uint4 v; } o;
    o.us[0] = f2bf(a.x); o.us[1] = f2bf(a.y); o.us[2] = f2bf(a.z); o.us[3] = f2bf(a.w);
    o.us[4] = f2bf(b.x); o.us[5] = f2bf(b.y); o.us[6] = f2bf(b.z); o.us[7] = f2bf(b.w);
    ((uint4*)xb)[t] = o.v;
}

// ---------------------------------------------------------------------------
// Kernel 2: dequant -> W^T bf16  [OUT_F][IN_F]  via LDS transpose (round-2).
// ---------------------------------------------------------------------------
#define DQ_KP 32
#define DQ_N  64

__global__ __launch_bounds__(256) void dequant_kernel(const int* __restrict__ qw,
                                                      const int* __restrict__ qz,
                                                      const float* __restrict__ sc,
                                                      unsigned short* __restrict__ wt) {
    __shared__ unsigned short tile[DQ_N * DQ_KP * 8];   // 32 KB

    const int t   = threadIdx.x;
    const int kp0 = blockIdx.x * DQ_KP;
    const int n0  = blockIdx.y * DQ_N;

    // ---- phase 1: coalesced read + dequant -> LDS [n][k] ----
    {
        const int kp_l = t >> 3;            // 0..31
        const int nq   = t & 7;             // which 8-n chunk
        const int kp   = kp0 + kp_l;
        const int g    = kp >> 4;           // k-group (GROUP=128 = 16 kp)
        const int nb   = n0 + nq * 8;

        const uint4 q0 = *(const uint4*)&qw[(size_t)kp * OUT_F + nb];
        const uint4 q1 = *(const uint4*)&qw[(size_t)kp * OUT_F + nb + 4];
        const unsigned zq = (unsigned)qz[g * (OUT_F / 8) + (nb >> 3)];
        const float4 s0 = *(const float4*)&sc[(size_t)g * OUT_F + nb];
        const float4 s1 = *(const float4*)&sc[(size_t)g * OUT_F + nb + 4];

        unsigned qv[8] = {q0.x, q0.y, q0.z, q0.w, q1.x, q1.y, q1.z, q1.w};
        float    sv[8] = {s0.x, s0.y, s0.z, s0.w, s1.x, s1.y, s1.z, s1.w};

#pragma unroll
        for (int c = 0; c < 8; ++c) {
            const unsigned q = qv[c];
            const float zero = (float)(((zq >> (4 * c)) & 15u) + 1u);
            const float s = sv[c];
            union { unsigned short us[8]; uint4 v; } o;
#pragma unroll
            for (int j = 0; j < 8; ++j) {
                const float w = (float)((q >> (4 * j)) & 15u);
                o.us[j] = f2bf(s * (w - zero));
            }
            *(uint4*)&tile[(nq * 8 + c) * (DQ_KP * 8) + kp_l * 8] = o.v;
        }
    }

    __syncthreads();

    // ---- phase 2: LDS -> global, coalesced along k ----
    {
        const int chunk = t & 31;
        const int nw    = t >> 5;
#pragma unroll
        for (int p = 0; p < 8; ++p) {
            const int n_l = p * 8 + nw;
            const uint4 v = *(const uint4*)&tile[n_l * (DQ_KP * 8) + chunk * 8];
            *(uint4*)&wt[(size_t)(n0 + n_l) * IN_F + kp0 * 8 + chunk * 8] = v;
        }
    }
}

// ---------------------------------------------------------------------------
// Kernel 3: bf16 MFMA GEMM, 128x128 tile, BK=32, 4 waves (2x2).
//
// NEW (round 3): LDS tiles stored in MFMA-FRAGMENT order to kill the 8-way
// bank conflicts on ds_read_b128.
//   LDS chunk mt (0..7) = 1024 B holding the A-fragments of 16 rows:
//     byte [mt*1024 + i*16] = A[m0 + mt*16 + (i&15)][kt + (i>>4)*8 .. +7]
//   Fragment read: addr = mt*1024 + lane*16  -> linear, conflict-free.
//   Staging lane map: lane i fetches global row (i&15), k-chunk (i>>4).
//   Global coalescing unchanged (16 rows x 64 B segments per instruction).
// ---------------------------------------------------------------------------
__global__ __launch_bounds__(256) void gemm_kernel(const unsigned short* __restrict__ xb,
                                                   const unsigned short* __restrict__ wt,
                                                   const float* __restrict__ bias,
                                                   float* __restrict__ out) {
    __shared__ unsigned short As[BM * BK];   // 8 KB, fragment-ordered
    __shared__ unsigned short Bs[BN * BK];   // 8 KB, fragment-ordered

    const int tid  = threadIdx.x;
    const int wid  = tid >> 6;
    const int lane = tid & 63;
    const int m0 = blockIdx.y * BM;
    const int n0 = blockIdx.x * BN;
    const int wave_m = wid & 1;
    const int wave_n = wid >> 1;

    floatx4 acc[4][4] = {};

    // staging lane map: row = lane&15, k-chunk = lane>>4 (8 elems = 16 B)
    const int srow = lane & 15;
    const int skq  = (lane >> 4) * 8;
    const unsigned short* ga0 = xb + (size_t)(m0 + (wid + 0) * 16 + srow) * IN_F + skq;
    const unsigned short* ga1 = xb + (size_t)(m0 + (wid + 4) * 16 + srow) * IN_F + skq;
    const unsigned short* gb0 = wt + (size_t)(n0 + (wid + 0) * 16 + srow) * IN_F + skq;
    const unsigned short* gb1 = wt + (size_t)(n0 + (wid + 4) * 16 + srow) * IN_F + skq;
    unsigned short* la0 = &As[(wid + 0) * 512];   // chunk mt = wid
    unsigned short* la1 = &As[(wid + 4) * 512];   // chunk mt = wid+4
    unsigned short* lb0 = &Bs[(wid + 0) * 512];
    unsigned short* lb1 = &Bs[(wid + 4) * 512];

    // fragment read bases (shorts): chunk*(512) + lane*8
    const int a_base = wave_m * 4 * 512 + lane * 8;
    const int b_base = wave_n * 4 * 512 + lane * 8;

    for (int kt = 0; kt < IN_F; kt += BK) {
        __syncthreads();
        load_lds16(ga0 + kt, la0);
        load_lds16(ga1 + kt, la1);
        load_lds16(gb0 + kt, lb0);
        load_lds16(gb1 + kt, lb1);
        __syncthreads();

        short8 a[4], b[4];
#pragma unroll
        for (int i = 0; i < 4; ++i)
            a[i] = *(const short8*)&As[a_base + i * 512];
#pragma unroll
        for (int j = 0; j < 4; ++j)
            b[j] = *(const short8*)&Bs[b_base + j * 512];
#pragma unroll
        for (int i = 0; i < 4; ++i)
#pragma unroll
            for (int j = 0; j < 4; ++j)
                acc[i][j] = __builtin_amdgcn_mfma_f32_16x16x32_bf16(a[i], b[j], acc[i][j], 0, 0, 0);
    }

    // epilogue: C/D layout col = lane&15, row = (lane>>4)*4 + reg
    const int mrow = m0 + wave_m * 64 + (lane >> 4) * 4;
    const int ncol = n0 + wave_n * 64 + (lane & 15);
#pragma unroll
    for (int j = 0; j < 4; ++j) {
        const int n = ncol + j * 16;
        const float bv = bias[n];
#pragma unroll
        for (int i = 0; i < 4; ++i) {
            const int m = mrow + i * 16;
#pragma unroll
            for (int r = 0; r < 4; ++r)
                out[(size_t)(m + r) * OUT_F + n] = acc[i][j][r] + bv;
        }
    }
}

extern "C" void kernel_launch(void* const* d_in, const int* in_sizes, int n_in,
                              void* d_out, int out_size, void* d_ws, size_t ws_size,
                              hipStream_t stream) {
    const float* x    = (const float*)d_in[0];
    const int*   qw   = (const int*)d_in[1];
    const int*   qz   = (const int*)d_in[2];
    const float* sc   = (const float*)d_in[3];
    const float* bias = (const float*)d_in[4];
    float* out = (float*)d_out;

    unsigned short* xb = (unsigned short*)d_ws;                       // 64 MiB
    unsigned short* wt = xb + (size_t)M_ROWS * IN_F;                  // +32 MiB

    convert_x_kernel<<<(M_ROWS * IN_F / 8) / 256, 256, 0, stream>>>(x, xb);
    dequant_kernel<<<dim3(IN_F / 8 / DQ_KP, OUT_F / DQ_N), 256, 0, stream>>>(qw, qz, sc, wt);
    gemm_kernel<<<dim3(OUT_F / BN, M_ROWS / BM), 256, 0, stream>>>(xb, wt, bias, out);
}

// Round 4
// 480.255 us; speedup vs baseline: 1.4523x; 1.4523x over previous
//
#include <hip/hip_runtime.h>
#include <hip/hip_bf16.h>

#define IN_F 4096
#define OUT_F 4096
#define M_ROWS 8192          // 4 * 2048
#define GROUP 128

#define BM 128
#define BN 128
#define BK 32
#define KT_TILES (IN_F / 32)   // 128 k-tiles per row-tile

// Tiled workspace layout ("fragment order"):
//   element [row][k] -> block ((row>>4)*KT_TILES + (k>>5)) of 512 shorts;
//   inner offset = (((k>>3)&3)*16 + (row&15))*8 + (k&7)
// so that global_load_lds (lds = base + lane*16) with per-lane gptr
// = tile_base + lane*16 stages a 1024 B CONTIGUOUS block that lands in LDS
// already in MFMA A/B fragment order (lane l = A[row=l&15][k=(l>>4)*8+j]).

typedef __attribute__((ext_vector_type(8))) short short8;
typedef __attribute__((ext_vector_type(4))) float floatx4;

__device__ __forceinline__ unsigned short f2bf(float f) {
    unsigned int u = __builtin_bit_cast(unsigned int, f);
    u += 0x7fffu + ((u >> 16) & 1u);   // RNE
    return (unsigned short)(u >> 16);
}

__device__ __forceinline__ void load_lds16(const unsigned short* g, unsigned short* l) {
    __builtin_amdgcn_global_load_lds(
        (const __attribute__((address_space(1))) void*)g,
        (__attribute__((address_space(3))) void*)l,
        16, 0, 0);
}

// ---------------------------------------------------------------------------
// Kernel 1: x fp32 -> xb_t bf16 tiled. Block: 16 rows x 256 k.
// Grid: (IN_F/256, M_ROWS/16) = (16, 512).
// ---------------------------------------------------------------------------
__global__ __launch_bounds__(256) void convert_x_kernel(const float* __restrict__ x,
                                                        unsigned short* __restrict__ xb) {
    __shared__ unsigned short tile[16 * 256];   // 8 KB, output (tiled) order

    const int t  = threadIdx.x;
    const int m0 = blockIdx.y * 16;
    const int k0 = blockIdx.x * 256;

    // phase 1: coalesced read (16 rows x 256 B segments), convert, LDS in tiled order
    {
        const int r = t & 15;
        const int c = t >> 4;                  // 0..15, 16 floats each
        const float4* src = (const float4*)(x + (size_t)(m0 + r) * IN_F + k0 + c * 16);
        float4 f[4];
#pragma unroll
        for (int i = 0; i < 4; ++i) f[i] = src[i];
        const float* fs = (const float*)f;
#pragma unroll
        for (int h = 0; h < 2; ++h) {          // two 8-element k-groups
            const int kl = c * 16 + h * 8;
            const int kt_l = kl >> 5;
            const int q    = (kl >> 3) & 3;
            union { unsigned short us[8]; uint4 v; } o;
#pragma unroll
            for (int j = 0; j < 8; ++j) o.us[j] = f2bf(fs[h * 8 + j]);
            *(uint4*)&tile[kt_l * 512 + (q * 16 + (t & 15)) * 8] = o.v;
        }
    }

    __syncthreads();

    // phase 2: linear copy LDS -> global (block's output is 8 KB contiguous)
    {
        unsigned short* dst = xb + ((size_t)blockIdx.y * KT_TILES + blockIdx.x * 8) * 512;
        *(uint4*)&dst[t * 8]        = *(const uint4*)&tile[t * 8];
        *(uint4*)&dst[2048 + t * 8] = *(const uint4*)&tile[2048 + t * 8];
    }
}

// ---------------------------------------------------------------------------
// Kernel 2: dequant -> wt_t bf16 tiled. Block: 64 n x 32 kp (=256 k).
// Grid: (512/32, 4096/64) = (16, 64).
// ---------------------------------------------------------------------------
#define DQ_KP 32
#define DQ_N  64

__global__ __launch_bounds__(256) void dequant_kernel(const int* __restrict__ qw,
                                                      const int* __restrict__ qz,
                                                      const float* __restrict__ sc,
                                                      unsigned short* __restrict__ wt) {
    __shared__ unsigned short tile[4 * 8 * 512];   // 32 KB: [tn_l][kt_l][512] tiled order

    const int t   = threadIdx.x;
    const int kp0 = blockIdx.x * DQ_KP;
    const int n0  = blockIdx.y * DQ_N;

    // phase 1: coalesced qweight read + dequant -> LDS in tiled order
    {
        const int kp_l = t >> 3;            // 0..31
        const int nq   = t & 7;             // 8-n chunk
        const int kp   = kp0 + kp_l;
        const int g    = kp >> 4;
        const int nb   = n0 + nq * 8;

        const uint4 q0 = *(const uint4*)&qw[(size_t)kp * OUT_F + nb];
        const uint4 q1 = *(const uint4*)&qw[(size_t)kp * OUT_F + nb + 4];
        const unsigned zq = (unsigned)qz[g * (OUT_F / 8) + (nb >> 3)];
        const float4 s0 = *(const float4*)&sc[(size_t)g * OUT_F + nb];
        const float4 s1 = *(const float4*)&sc[(size_t)g * OUT_F + nb + 4];

        unsigned qv[8] = {q0.x, q0.y, q0.z, q0.w, q1.x, q1.y, q1.z, q1.w};
        float    sv[8] = {s0.x, s0.y, s0.z, s0.w, s1.x, s1.y, s1.z, s1.w};

        const int kt_l  = kp_l >> 2;        // 0..7
        const int q_out = kp_l & 3;
        const int tn_l  = nq >> 1;

#pragma unroll
        for (int c = 0; c < 8; ++c) {
            const unsigned q = qv[c];
            const float zero = (float)(((zq >> (4 * c)) & 15u) + 1u);
            const float s = sv[c];
            const int r = (nq * 8 + c) & 15;
            union { unsigned short us[8]; uint4 v; } o;
#pragma unroll
            for (int j = 0; j < 8; ++j) {
                const float w = (float)((q >> (4 * j)) & 15u);
                o.us[j] = f2bf(s * (w - zero));
            }
            *(uint4*)&tile[(tn_l * 8 + kt_l) * 512 + (q_out * 16 + r) * 8] = o.v;
        }
    }

    __syncthreads();

    // phase 2: linear copy per n-tile (each tn_l = 8 KB contiguous in global)
    {
        const int tn0 = blockIdx.y * 4;
        const int kt0 = blockIdx.x * 8;
#pragma unroll
        for (int tn_l = 0; tn_l < 4; ++tn_l) {
            unsigned short* dst = wt + ((size_t)(tn0 + tn_l) * KT_TILES + kt0) * 512;
            const unsigned short* srcl = &tile[tn_l * 4096];
            *(uint4*)&dst[t * 8]        = *(const uint4*)&srcl[t * 8];
            *(uint4*)&dst[2048 + t * 8] = *(const uint4*)&srcl[2048 + t * 8];
        }
    }
}

// ---------------------------------------------------------------------------
// Kernel 3: bf16 MFMA GEMM, 128x128 tile, BK=32, 4 waves (2x2).
// Tiled inputs: staging = 1024 B contiguous per instruction, LDS lands in
// fragment order -> conflict-free lane*16 reads.
// ---------------------------------------------------------------------------
__global__ __launch_bounds__(256) void gemm_kernel(const unsigned short* __restrict__ xb,
                                                   const unsigned short* __restrict__ wt,
                                                   const float* __restrict__ bias,
                                                   float* __restrict__ out) {
    __shared__ unsigned short As[BM * BK];   // 8 KB, fragment order (8 chunks x 512)
    __shared__ unsigned short Bs[BN * BK];

    const int tid  = threadIdx.x;
    const int wid  = tid >> 6;
    const int lane = tid & 63;
    const int TM0 = blockIdx.y * 8;          // first m-tile (of 16 rows)
    const int TN0 = blockIdx.x * 8;
    const int wave_m = wid & 1;
    const int wave_n = wid >> 1;

    floatx4 acc[4][4] = {};

    // per-lane staging pointers: contiguous 1024 B per chunk
    const unsigned short* ga0 = xb + ((size_t)(TM0 + wid + 0) * KT_TILES) * 512 + lane * 8;
    const unsigned short* ga1 = xb + ((size_t)(TM0 + wid + 4) * KT_TILES) * 512 + lane * 8;
    const unsigned short* gb0 = wt + ((size_t)(TN0 + wid + 0) * KT_TILES) * 512 + lane * 8;
    const unsigned short* gb1 = wt + ((size_t)(TN0 + wid + 4) * KT_TILES) * 512 + lane * 8;
    unsigned short* la0 = &As[(wid + 0) * 512];
    unsigned short* la1 = &As[(wid + 4) * 512];
    unsigned short* lb0 = &Bs[(wid + 0) * 512];
    unsigned short* lb1 = &Bs[(wid + 4) * 512];

    const int a_base = wave_m * 4 * 512 + lane * 8;
    const int b_base = wave_n * 4 * 512 + lane * 8;

    for (int kt = 0; kt < KT_TILES; ++kt) {
        __syncthreads();
        load_lds16(ga0 + kt * 512, la0);
        load_lds16(ga1 + kt * 512, la1);
        load_lds16(gb0 + kt * 512, lb0);
        load_lds16(gb1 + kt * 512, lb1);
        __syncthreads();

        short8 a[4], b[4];
#pragma unroll
        for (int i = 0; i < 4; ++i)
            a[i] = *(const short8*)&As[a_base + i * 512];
#pragma unroll
        for (int j = 0; j < 4; ++j)
            b[j] = *(const short8*)&Bs[b_base + j * 512];
#pragma unroll
        for (int i = 0; i < 4; ++i)
#pragma unroll
            for (int j = 0; j < 4; ++j)
                acc[i][j] = __builtin_amdgcn_mfma_f32_16x16x32_bf16(a[i], b[j], acc[i][j], 0, 0, 0);
    }

    // epilogue: C/D layout col = lane&15, row = (lane>>4)*4 + reg
    const int mrow = TM0 * 16 + wave_m * 64 + (lane >> 4) * 4;
    const int ncol = TN0 * 16 + wave_n * 64 + (lane & 15);
#pragma unroll
    for (int j = 0; j < 4; ++j) {
        const int n = ncol + j * 16;
        const float bv = bias[n];
#pragma unroll
        for (int i = 0; i < 4; ++i) {
            const int m = mrow + i * 16;
#pragma unroll
            for (int r = 0; r < 4; ++r)
                out[(size_t)(m + r) * OUT_F + n] = acc[i][j][r] + bv;
        }
    }
}

extern "C" void kernel_launch(void* const* d_in, const int* in_sizes, int n_in,
                              void* d_out, int out_size, void* d_ws, size_t ws_size,
                              hipStream_t stream) {
    const float* x    = (const float*)d_in[0];
    const int*   qw   = (const int*)d_in[1];
    const int*   qz   = (const int*)d_in[2];
    const float* sc   = (const float*)d_in[3];
    const float* bias = (const float*)d_in[4];
    float* out = (float*)d_out;

    unsigned short* xb = (unsigned short*)d_ws;                       // 64 MiB tiled
    unsigned short* wt = xb + (size_t)M_ROWS * IN_F;                  // +32 MiB tiled

    convert_x_kernel<<<dim3(IN_F / 256, M_ROWS / 16), 256, 0, stream>>>(x, xb);
    dequant_kernel<<<dim3(IN_F / 8 / DQ_KP, OUT_F / DQ_N), 256, 0, stream>>>(qw, qz, sc, wt);
    gemm_kernel<<<dim3(OUT_F / BN, M_ROWS / BM), 256, 0, stream>>>(xb, wt, bias, out);
}